// Round 10
// baseline (57.462 us; speedup 1.0000x reference)
//
#include <hip/hip_runtime.h>

// GIoU max-match loss: out = (1/B) * sum_{b,p} (1 - max_g GIoU(pred[b,p], tgt[b,g]))
// B=32, P=2048, G=512 bench shape.
//
// R10: pruning with BLOCK-UNIFORM (scalar) decisions on the R4 skeleton.
//  prep (grid (2,B), 512thr): counting-sort targets (x=0) and preds (x=1) into
//    an 8x8 grid of 128px cells, SERPENTINE cell order (compact block hulls);
//    per-batch twMax/thMax.
//  main (512thr = 8 waves, NP=2 preds/lane, grid (P/128, B)):
//    lane <-> pred (all waves share the block's 128 preds); waves split targets;
//    all target reads wave-uniform broadcast (R4-proven inner loop).
//    Pass A: evaluate the pred-hull's +-1-cell rectangle (contiguous runs/row).
//    Exchange -> per-pred max -> scalar mBlkMin.
//    Pass B: uniform 64-cell loop; skip cell when provable bound
//      ub = min((pwMax+twMax)/Dx, (phMax+thMax)/Dy) [+1 if overlap possible]
//    is <= mBlkMin - 1e-3 (Dx,Dy = hull-to-cell-edge distances; ow>=dxc,
//    oh>=ph,th derivations; disjoint when D >= (pwMax+twMax)/2). Skipped cells
//    cost ZERO per-lane work. Pruning is exact (strict-margin upper bound).
//  reduce: tiny second kernel (deterministic).
// Math (w,h>=1 after +1 fold): outer via a+b-min identity, no clamps; un>=1;
//   gi+1 = inter*rcp(un) + un*rcp(outer) in (0,2]; clip/eps no-ops at thr 42.24.

constexpr int NCX = 8, NCELL = 64;
constexpr float CELL = 128.0f, INV_CELL = 1.0f / 128.0f;
constexpr int GCAP = 1024;      // LDS target capacity (bench: 512)
constexpr int NP = 2, NW = 8;

__device__ __forceinline__ int cell_xy(float c) {
    int i = (int)(c * INV_CELL);
    return min(NCX - 1, max(0, i));
}
__device__ __forceinline__ int snake_id(int cx, int cy) {
    return cy * NCX + ((cy & 1) ? (NCX - 1 - cx) : cx);
}

template <int CTRL>
__device__ __forceinline__ float dppmaxs(float x) {
    int i = __float_as_int(x);
    int m = __builtin_amdgcn_update_dpp(i, i, CTRL, 0xF, 0xF, false);
    return fmaxf(x, __int_as_float(m));
}
template <int CTRL>
__device__ __forceinline__ float dppmins(float x) {
    int i = __float_as_int(x);
    int m = __builtin_amdgcn_update_dpp(i, i, CTRL, 0xF, 0xF, false);
    return fminf(x, __int_as_float(m));
}
// full-wave folds; valid in lane 63
__device__ __forceinline__ float dpp_allmax(float x) {
    x = dppmaxs<0x111>(x); x = dppmaxs<0x112>(x); x = dppmaxs<0x114>(x);
    x = dppmaxs<0x118>(x); x = dppmaxs<0x142>(x); x = dppmaxs<0x143>(x);
    return x;
}
__device__ __forceinline__ float dpp_allmin(float x) {
    x = dppmins<0x111>(x); x = dppmins<0x112>(x); x = dppmins<0x114>(x);
    x = dppmins<0x118>(x); x = dppmins<0x142>(x); x = dppmins<0x143>(x);
    return x;
}
__device__ __forceinline__ float rfl(float x) {
    return __int_as_float(__builtin_amdgcn_readfirstlane(__float_as_int(x)));
}

__global__ __launch_bounds__(512) void giou_prep_kernel(
    const float4* __restrict__ tgt, const float4* __restrict__ pred,
    float4* __restrict__ sortedT, float* __restrict__ sTA,
    float4* __restrict__ sortedP,
    int* __restrict__ tstartG, float* __restrict__ twhMaxG,
    int P, int G)
{
    __shared__ int cnt[NCELL], cstart[NCELL + 1];
    __shared__ int sTw, sTh;
    const int b = blockIdx.y, part = blockIdx.x, tid = threadIdx.x;

    if (tid < NCELL) cnt[tid] = 0;
    if (tid == 0) { sTw = 0; sTh = 0; }
    __syncthreads();

    const int N = (part == 0) ? G : P;
    const float4* __restrict__ src = (part == 0) ? (tgt + (size_t)b * G)
                                                 : (pred + (size_t)b * P);
    // fixed 4-step unroll: ranks live in registers (supports N <= 2048)
    int myr0 = 0, myr1 = 0, myr2 = 0, myr3 = 0;
    #pragma unroll
    for (int it = 0; it < 4; ++it) {
        int i = tid + it * 512;
        if (i < N) {
            float4 t = src[i]; t.z += 1.0f; t.w += 1.0f;
            int c = snake_id(cell_xy((t.x + t.z) * 0.5f), cell_xy((t.y + t.w) * 0.5f));
            int r = atomicAdd(&cnt[c], 1);
            if (it == 0) myr0 = r; else if (it == 1) myr1 = r;
            else if (it == 2) myr2 = r; else myr3 = r;
            if (part == 0) {
                atomicMax(&sTw, __float_as_int(t.z - t.x));
                atomicMax(&sTh, __float_as_int(t.w - t.y));
            }
        }
    }
    __syncthreads();
    if (tid == 0) {
        int s = 0;
        for (int c = 0; c < NCELL; ++c) { cstart[c] = s; s += cnt[c]; }
        cstart[NCELL] = s;
    }
    __syncthreads();
    #pragma unroll
    for (int it = 0; it < 4; ++it) {
        int i = tid + it * 512;
        if (i < N) {
            float4 t = src[i]; t.z += 1.0f; t.w += 1.0f;
            int c = snake_id(cell_xy((t.x + t.z) * 0.5f), cell_xy((t.y + t.w) * 0.5f));
            int r = (it == 0) ? myr0 : (it == 1) ? myr1 : (it == 2) ? myr2 : myr3;
            int pos = cstart[c] + r;
            if (part == 0) {
                sortedT[(size_t)b * G + pos] = t;
                sTA[(size_t)b * G + pos] = (t.z - t.x) * (t.w - t.y);
            } else {
                sortedP[(size_t)b * P + pos] = t;
            }
        }
    }
    if (part == 0) {
        if (tid <= NCELL) tstartG[b * (NCELL + 1) + tid] = cstart[tid];
        if (tid == 0) {
            twhMaxG[2 * b]     = __int_as_float(sTw);
            twhMaxG[2 * b + 1] = __int_as_float(sTh);
        }
    }
}

__global__ __launch_bounds__(512, 4) void giou_main_kernel(
    const float4* __restrict__ sortedT, const float* __restrict__ sTA,
    const float4* __restrict__ sortedP,
    const int* __restrict__ tstartG, const float* __restrict__ twhMaxG,
    float* __restrict__ partial, int P, int G)
{
    __shared__ float4 sT[GCAP];
    __shared__ float  sA[GCAP];
    __shared__ int    sStart[NCELL + 1];
    __shared__ float  sEx[NP][512];
    __shared__ float  sH[6][NW];     // hx0,hx1,hy0,hy1,pwMax,phMax per wave
    __shared__ float  sScal[1];

    const int b = blockIdx.y, tid = threadIdx.x, lane = tid & 63, wid = tid >> 6;
    const int GL = min(G, GCAP);

    for (int i = tid; i < GL; i += 512) {
        sT[i] = sortedT[(size_t)b * G + i];
        sA[i] = sTA[(size_t)b * G + i];
    }
    if (tid <= NCELL) sStart[tid] = min(tstartG[b * (NCELL + 1) + tid], GL);

    const int base = blockIdx.x * (NP * 64);
    float4 pb[NP]; float pw[NP], ph[NP], pa[NP];
    #pragma unroll
    for (int k = 0; k < NP; ++k) {
        float4 v = sortedP[(size_t)b * P + min(base + 64 * k + lane, P - 1)];
        pb[k] = v; pw[k] = v.z - v.x; ph[k] = v.w - v.y; pa[k] = pw[k] * ph[k];
    }
    // hull candidates (per lane, over both preds)
    float cxa = (pb[0].x + pb[0].z) * 0.5f, cya = (pb[0].y + pb[0].w) * 0.5f;
    float cxb = (pb[1].x + pb[1].z) * 0.5f, cyb = (pb[1].y + pb[1].w) * 0.5f;
    float vx0 = dpp_allmin(fminf(cxa, cxb));
    float vx1 = dpp_allmax(fmaxf(cxa, cxb));
    float vy0 = dpp_allmin(fminf(cya, cyb));
    float vy1 = dpp_allmax(fmaxf(cya, cyb));
    float vpw = dpp_allmax(fmaxf(pw[0], pw[1]));
    float vph = dpp_allmax(fmaxf(ph[0], ph[1]));
    if (lane == 63) {
        sH[0][wid] = vx0; sH[1][wid] = vx1; sH[2][wid] = vy0;
        sH[3][wid] = vy1; sH[4][wid] = vpw; sH[5][wid] = vph;
    }
    __syncthreads();          // also covers sT/sA/sStart staging

    float hx0 = sH[0][0], hx1 = sH[1][0], hy0 = sH[2][0], hy1 = sH[3][0];
    float pwMax = sH[4][0], phMax = sH[5][0];
    #pragma unroll
    for (int w = 1; w < NW; ++w) {
        hx0 = fminf(hx0, sH[0][w]); hx1 = fmaxf(hx1, sH[1][w]);
        hy0 = fminf(hy0, sH[2][w]); hy1 = fmaxf(hy1, sH[3][w]);
        pwMax = fmaxf(pwMax, sH[4][w]); phMax = fmaxf(phMax, sH[5][w]);
    }
    hx0 = rfl(hx0); hx1 = rfl(hx1); hy0 = rfl(hy0); hy1 = rfl(hy1);
    pwMax = rfl(pwMax); phMax = rfl(phMax);

    const int rcx0 = max(0, __builtin_amdgcn_readfirstlane(cell_xy(hx0) - 1));
    const int rcx1 = min(NCX - 1, __builtin_amdgcn_readfirstlane(cell_xy(hx1) + 1));
    const int rcy0 = max(0, __builtin_amdgcn_readfirstlane(cell_xy(hy0) - 1));
    const int rcy1 = min(NCX - 1, __builtin_amdgcn_readfirstlane(cell_xy(hy1) + 1));

    float m[NP] = {0.0f, 0.0f};       // running max of giou+1

    auto evalTA = [&](float4 t, float ta) {
        float tw = t.z - t.x, th = t.w - t.y;
        #pragma unroll
        for (int k = 0; k < NP; ++k) {
            float iwr = fminf(pb[k].z, t.z) - fmaxf(pb[k].x, t.x);
            float ihr = fminf(pb[k].w, t.w) - fmaxf(pb[k].y, t.y);
            float inter = fmaxf(iwr, 0.0f) * fmaxf(ihr, 0.0f);
            float un = (pa[k] + ta) - inter;                        // >= 1
            float outer = ((pw[k] + tw) - iwr) * ((ph[k] + th) - ihr);
            float gi = __builtin_fmaf(un, __builtin_amdgcn_rcpf(outer),
                                      inter * __builtin_amdgcn_rcpf(un));
            m[k] = fmaxf(m[k], gi);
        }
    };

    // Pass A: hull rectangle +-1 cell; contiguous serpentine run per row
    for (int cy = rcy0; cy <= rcy1; ++cy) {
        int a = snake_id(rcx0, cy), c2 = snake_id(rcx1, cy);
        int idLo = min(a, c2), idHi = max(a, c2);
        const int lo = sStart[idLo], hi = sStart[idHi + 1];
        for (int i = lo + wid; i < hi; i += NW) evalTA(sT[i], sA[i]);
    }

    sEx[0][tid] = m[0]; sEx[1][tid] = m[1];
    __syncthreads();
    #pragma unroll
    for (int k = 0; k < NP; ++k) {
        float mm = sEx[k][lane];
        #pragma unroll
        for (int w = 1; w < NW; ++w) mm = fmaxf(mm, sEx[k][w * 64 + lane]);
        m[k] = mm;
    }
    if (wid == 0) {
        float l = dpp_allmin(fminf(m[0], m[1]));
        if (lane == 63) sScal[0] = l;
    }
    __syncthreads();
    const float mThresh = rfl(sScal[0]) - 1e-3f;

    const float twMaxB = twhMaxG[2 * b];
    const float thMaxB = twhMaxG[2 * b + 1];

    // Pass B: uniform 64-cell loop with scalar bound; skipped cell = 0 work
    for (int c = 0; c < NCELL; ++c) {
        const int lo = sStart[c], hi = sStart[c + 1];
        if (lo == hi) continue;
        const int cy = c >> 3;
        const int cxs = c & 7;
        const int cx = (cy & 1) ? (NCX - 1 - cxs) : cxs;
        if (cx >= rcx0 && cx <= rcx1 && cy >= rcy0 && cy <= rcy1) continue;
        float cellXlo = (cx == 0) ? -1e30f : cx * CELL;
        float cellXhi = (cx == NCX - 1) ? 1e30f : (cx + 1) * CELL;
        float cellYlo = (cy == 0) ? -1e30f : cy * CELL;
        float cellYhi = (cy == NCX - 1) ? 1e30f : (cy + 1) * CELL;
        float Dx = fmaxf(0.0f, fmaxf(cellXlo - hx1, hx0 - cellXhi));
        float Dy = fmaxf(0.0f, fmaxf(cellYlo - hy1, hy0 - cellYhi));
        bool disj = (Dx >= 0.5f * (pwMax + twMaxB)) || (Dy >= 0.5f * (phMax + thMaxB));
        float ubx = (Dx > 0.0f) ? (pwMax + twMaxB) * __builtin_amdgcn_rcpf(Dx) : 1e30f;
        float uby = (Dy > 0.0f) ? (phMax + thMaxB) * __builtin_amdgcn_rcpf(Dy) : 1e30f;
        float ub = fminf(ubx, uby) * 1.01f + (disj ? 0.0f : 1.0f);
        if (ub <= mThresh) continue;                     // uniform skip
        for (int i = lo + wid; i < hi; i += NW) evalTA(sT[i], sA[i]);
    }
    // overflow tail (G > GCAP only; bench never hits)
    for (int i = GL + wid; i < G; i += NW)
        evalTA(sortedT[(size_t)b * G + i], sTA[(size_t)b * G + i]);

    sEx[0][tid] = m[0]; sEx[1][tid] = m[1];
    __syncthreads();
    if (wid == 0) {
        float v = 0.0f;
        #pragma unroll
        for (int k = 0; k < NP; ++k) {
            float mm = sEx[k][lane];
            #pragma unroll
            for (int w = 1; w < NW; ++w) mm = fmaxf(mm, sEx[k][w * 64 + lane]);
            v += (base + 64 * k + lane < P) ? (2.0f - mm) : 0.0f;   // 1 - giou
        }
        #pragma unroll
        for (int off = 32; off > 0; off >>= 1) v += __shfl_down(v, off, 64);
        if (lane == 0) partial[blockIdx.y * gridDim.x + blockIdx.x] = v;
    }
}

__global__ __launch_bounds__(256) void giou_reduce_kernel(
    const float* __restrict__ partial, float* __restrict__ out, int n, float invB)
{
    const int tid = threadIdx.x;
    float v = 0.0f;
    for (int i = tid; i < n; i += 256) v += partial[i];
    #pragma unroll
    for (int off = 32; off > 0; off >>= 1) v += __shfl_down(v, off, 64);
    __shared__ float sW[4];
    const int wid = tid >> 6;
    if ((tid & 63) == 0) sW[wid] = v;
    __syncthreads();
    if (tid == 0) out[0] = (sW[0] + sW[1] + sW[2] + sW[3]) * invB;
}

extern "C" void kernel_launch(void* const* d_in, const int* in_sizes, int n_in,
                              void* d_out, int out_size, void* d_ws, size_t ws_size,
                              hipStream_t stream) {
    const float* imgs_box = (const float*)d_in[0];  // (B, G, 4) fp32 targets
    const float* pre_box  = (const float*)d_in[1];  // (B, P, 4) fp32 preds
    const int B = in_sizes[2];
    const int G = in_sizes[0] / (4 * B);
    const int P = in_sizes[1] / (4 * B);

    char* w = (char*)d_ws;
    auto alloc = [&](size_t bytes) {
        char* r = w; w += (bytes + 15) & ~size_t(15); return r;
    };
    float4* sortedT = (float4*)alloc((size_t)B * G * 16);
    float*  sTA     = (float*) alloc((size_t)B * G * 4);
    float4* sortedP = (float4*)alloc((size_t)B * P * 16);
    int*    tstartG = (int*)   alloc((size_t)B * (NCELL + 1) * 4);
    float*  twhMaxG = (float*) alloc((size_t)B * 2 * 4);
    const int pblocks = (P + NP * 64 - 1) / (NP * 64);   // 128 preds/block
    float*  partial = (float*) alloc((size_t)pblocks * B * 4);

    dim3 pgrid(2, B);
    giou_prep_kernel<<<pgrid, 512, 0, stream>>>(
        (const float4*)imgs_box, (const float4*)pre_box,
        sortedT, sTA, sortedP, tstartG, twhMaxG, P, G);

    dim3 grid(pblocks, B);
    giou_main_kernel<<<grid, 512, 0, stream>>>(
        sortedT, sTA, sortedP, tstartG, twhMaxG, partial, P, G);

    giou_reduce_kernel<<<1, 256, 0, stream>>>(
        partial, (float*)d_out, pblocks * B, 1.0f / (float)B);
}

// Round 11
// 34.882 us; speedup vs baseline: 1.6473x; 1.6473x over previous
//
#include <hip/hip_runtime.h>

// GIoU max-match loss: out = (1/B) * sum_{b,p} (1 - max_g GIoU(pred[b,p], tgt[b,g]))
// B=32, P=2048, G=512 bench shape.
//
// R11 = R4's proven skeleton + two fixes aimed at its ~40% issue efficiency:
//  1) z-split (NZ=2): grid (P/128, B, NZ) = 1024 blocks -> 4 blocks/CU
//     (2048 thr = CU max) = 32 waves/CU, so lgkmcnt stalls & barriers hide.
//     Each slice writes per-pred max(giou+1) to maxM[z][b][p]; reduce kernel
//     max-combines slices, sums losses, atomicAdd (d_out zeroed by memset).
//  2) depth-2 software pipeline on the target stream: sT[g+2] issued before
//     evaluating t0, so the ~120-cyc ds_read latency lands behind ~92 cyc of
//     independent VALU work instead of in front of it.
// Inner loop unchanged from R4 (NP=2 preds/lane, broadcast LDS reads, no
// bank conflicts). Math: boxes have w,h >= 1 after the +1 fold; outer dims
// via a+b-min identity (no clamps), un >= 1; gi+1 = inter*rcp(un) +
// un*rcp(outer) in (0,2]; reference's [-1,1] clip and 1e-6 iou floor are
// no-ops at the 42.24 absmax threshold.

constexpr int NP = 2;       // preds per lane
constexpr int NW = 8;       // waves per block
constexpr int NZ = 2;       // target slices (blockIdx.z)
constexpr int GCAP = 1024;  // per-slice LDS capacity (bench uses 256)

__global__ __launch_bounds__(512, 8) void giou_max_kernel(
    const float4* __restrict__ tgt,    // (B, G) boxes (x1,y1,x2,y2)
    const float4* __restrict__ pred,   // (B, P) boxes
    float* __restrict__ maxM,          // [NZ][B][P] per-slice max of giou+1
    int P, int G)
{
    __shared__ float4 sT[GCAP + 2];
    __shared__ float  sA[GCAP + 2];
    __shared__ float  sEx[NP][512];

    const int b = blockIdx.y, z = blockIdx.z;
    const int tid = threadIdx.x, lane = tid & 63, wid = tid >> 6;

    const int Gz  = (G + NZ - 1) / NZ;
    const int zlo = z * Gz;
    const int cnt = min(Gz, G - zlo);          // targets in this slice
    const int CL  = min(cnt, GCAP);

    for (int i = tid; i < CL; i += 512) {
        float4 t = tgt[(size_t)b * G + zlo + i];
        t.z += 1.0f; t.w += 1.0f;              // fold the +1 convention
        sT[i] = t;
        sA[i] = (t.z - t.x) * (t.w - t.y);     // w,h >= 1: no clamp
    }
    if (tid < 2) {                             // pipeline pad (never evaluated)
        sT[CL + tid] = make_float4(0.f, 0.f, 1.f, 1.f);
        sA[CL + tid] = 1.0f;
    }

    const int base = blockIdx.x * (NP * 64);
    float4 pb[NP]; float pw[NP], ph[NP], pa[NP];
    #pragma unroll
    for (int k = 0; k < NP; ++k) {
        float4 v = pred[(size_t)b * P + min(base + 64 * k + lane, P - 1)];
        v.z += 1.0f; v.w += 1.0f;
        pb[k] = v; pw[k] = v.z - v.x; ph[k] = v.w - v.y; pa[k] = pw[k] * ph[k];
    }
    __syncthreads();

    const int gq = (CL + NW - 1) / NW;
    const int g0 = wid * gq;
    const int g1 = min(g0 + gq, CL);

    float m[NP] = {0.0f, 0.0f};                // running max of giou+1

    // depth-2 software pipeline (prime indices stay inside the padded array)
    float4 t0 = sT[g0], t1 = sT[g0 + 1];
    float  a0 = sA[g0], a1 = sA[g0 + 1];

    #pragma unroll 2
    for (int g = g0; g < g1; ++g) {
        float4 t2 = sT[g + 2];                 // issued before t0's math
        float  a2 = sA[g + 2];
        const float tw = t0.z - t0.x, th = t0.w - t0.y;
        #pragma unroll
        for (int k = 0; k < NP; ++k) {
            float iwr = fminf(pb[k].z, t0.z) - fmaxf(pb[k].x, t0.x);
            float ihr = fminf(pb[k].w, t0.w) - fmaxf(pb[k].y, t0.y);
            float inter = fmaxf(iwr, 0.0f) * fmaxf(ihr, 0.0f);
            float un = (pa[k] + a0) - inter;                     // >= 1
            float outer = ((pw[k] + tw) - iwr) * ((ph[k] + th) - ihr);
            float gi = __builtin_fmaf(un, __builtin_amdgcn_rcpf(outer),
                                      inter * __builtin_amdgcn_rcpf(un));
            m[k] = fmaxf(m[k], gi);
        }
        t0 = t1; a0 = a1; t1 = t2; a1 = a2;
    }

    // generic overflow tail (cnt > GCAP never happens in bench shapes)
    for (int g = GCAP + wid; g < cnt; g += NW) {
        float4 t = tgt[(size_t)b * G + zlo + g];
        t.z += 1.0f; t.w += 1.0f;
        float ta = (t.z - t.x) * (t.w - t.y);
        const float tw = t.z - t.x, th = t.w - t.y;
        #pragma unroll
        for (int k = 0; k < NP; ++k) {
            float iwr = fminf(pb[k].z, t.z) - fmaxf(pb[k].x, t.x);
            float ihr = fminf(pb[k].w, t.w) - fmaxf(pb[k].y, t.y);
            float inter = fmaxf(iwr, 0.0f) * fmaxf(ihr, 0.0f);
            float un = (pa[k] + ta) - inter;
            float outer = ((pw[k] + tw) - iwr) * ((ph[k] + th) - ihr);
            float gi = __builtin_fmaf(un, __builtin_amdgcn_rcpf(outer),
                                      inter * __builtin_amdgcn_rcpf(un));
            m[k] = fmaxf(m[k], gi);
        }
    }

    sEx[0][tid] = m[0]; sEx[1][tid] = m[1];
    __syncthreads();

    if (wid == 0) {
        #pragma unroll
        for (int k = 0; k < NP; ++k) {
            float mm = sEx[k][lane];
            #pragma unroll
            for (int w = 1; w < NW; ++w) mm = fmaxf(mm, sEx[k][w * 64 + lane]);
            int p = base + 64 * k + lane;
            if (p < P)
                maxM[((size_t)z * gridDim.y + b) * P + p] = mm;   // coalesced
        }
    }
}

__global__ __launch_bounds__(256) void giou_reduce_kernel(
    const float* __restrict__ maxM, float* __restrict__ out,
    int n, int nz, float invB)
{
    const int tid = threadIdx.x;
    float v = 0.0f;
    for (int i = blockIdx.x * 256 + tid; i < n; i += gridDim.x * 256) {
        float mm = maxM[i];
        for (int z = 1; z < nz; ++z) mm = fmaxf(mm, maxM[(size_t)z * n + i]);
        v += 2.0f - mm;                        // loss = 1 - giou = 2 - (giou+1)
    }
    #pragma unroll
    for (int off = 32; off > 0; off >>= 1) v += __shfl_down(v, off, 64);
    __shared__ float sW[4];
    const int wid = tid >> 6;
    if ((tid & 63) == 0) sW[wid] = v;
    __syncthreads();
    if (tid == 0)
        atomicAdd(out, (sW[0] + sW[1] + sW[2] + sW[3]) * invB);
}

extern "C" void kernel_launch(void* const* d_in, const int* in_sizes, int n_in,
                              void* d_out, int out_size, void* d_ws, size_t ws_size,
                              hipStream_t stream) {
    const float* imgs_box = (const float*)d_in[0];  // (B, G, 4) fp32 targets
    const float* pre_box  = (const float*)d_in[1];  // (B, P, 4) fp32 preds
    const int B = in_sizes[2];
    const int G = in_sizes[0] / (4 * B);
    const int P = in_sizes[1] / (4 * B);

    float* maxM = (float*)d_ws;                     // NZ * B * P floats

    hipMemsetAsync(d_out, 0, sizeof(float), stream);

    const int pblocks = (P + NP * 64 - 1) / (NP * 64);   // 128 preds/block
    dim3 grid(pblocks, B, NZ);
    giou_max_kernel<<<grid, 512, 0, stream>>>(
        (const float4*)imgs_box, (const float4*)pre_box, maxM, P, G);

    const int n = B * P;
    giou_reduce_kernel<<<64, 256, 0, stream>>>(
        maxM, (float*)d_out, n, NZ, 1.0f / (float)B);
}

// Round 12
// 33.230 us; speedup vs baseline: 1.7292x; 1.0497x over previous
//
#include <hip/hip_runtime.h>

// GIoU max-match loss: out = (1/B) * sum_{b,p} (1 - max_g GIoU(pred[b,p], tgt[b,g]))
// B=32, P=2048, G=512 bench shape.
//
// R12 = consolidated optimum. Evidence from R1-R11:
//   - cost is instruction-volume-bound at a fixed effective issue rate
//     (~53% of the m07 pure-FMA ceiling; invariant across occupancy 2-8
//     waves/SIMD, LDS vs register operands, rcp vs division-free, NP=1/2/4)
//   - so: proven R4 skeleton (512thr = 8 waves, NP=2 preds/lane, waves split
//     targets, broadcast LDS reads), division-free inner (no transcendentals),
//     single dispatch (block partial -> atomicAdd), and per-g shared work cut
//     to 2 ds_reads by pre-staging (tw,th,ta) alongside the box.
// Math (w,h >= 1 after the +1 fold): outer dims via a+b-min identity (no
//   clamps), un >= 1; giou+1 = num/den, num = un^2 + inter*outer,
//   den = un*outer; running max by cross-multiplication (num*denM > numM*den,
//   products <= ~5e19 fit fp32); one v_rcp per pred at the end. Reference's
//   [-1,1] clip and 1e-6 iou floor are no-ops at the 42.24 absmax threshold;
//   atomicAdd order variance ~1e-4.

constexpr int NP = 2;       // preds per lane
constexpr int NW = 8;       // waves per block
constexpr int GCAP = 1024;  // LDS target capacity (bench: 512)

__global__ __launch_bounds__(512) void giou_kernel(
    const float4* __restrict__ tgt,    // (B, G) boxes (x1,y1,x2,y2)
    const float4* __restrict__ pred,   // (B, P) boxes
    float* __restrict__ out,           // scalar, pre-zeroed
    int P, int G, float invB)
{
    __shared__ float4 sTB[GCAP];       // (x1, y1, x2+1, y2+1)
    __shared__ float4 sTD[GCAP];       // (tw, th, ta, 0)
    __shared__ float  sEx[NP][512];    // cross-wave max exchange

    const int b = blockIdx.y, tid = threadIdx.x;
    const int lane = tid & 63, wid = tid >> 6;
    const int GL = min(G, GCAP);

    // stage targets: box + derived dims/area (coalesced b128 loads)
    for (int i = tid; i < GL; i += 512) {
        float4 t = tgt[(size_t)b * G + i];
        t.z += 1.0f; t.w += 1.0f;              // fold the +1 convention
        float tw = t.z - t.x, th = t.w - t.y;  // >= 1, no clamp
        sTB[i] = t;
        sTD[i] = make_float4(tw, th, tw * th, 0.0f);
    }

    const int base = blockIdx.x * (NP * 64);
    float4 pb[NP]; float pw[NP], ph[NP], pa[NP];
    #pragma unroll
    for (int k = 0; k < NP; ++k) {
        float4 v = pred[(size_t)b * P + min(base + 64 * k + lane, P - 1)];
        v.z += 1.0f; v.w += 1.0f;
        pb[k] = v; pw[k] = v.z - v.x; ph[k] = v.w - v.y; pa[k] = pw[k] * ph[k];
    }
    __syncthreads();

    // wave w scans targets [w*gq, (w+1)*gq)
    const int gq = (GL + NW - 1) / NW;
    const int g0 = wid * gq, g1 = min(g0 + gq, GL);

    // running max of (giou+1) as fraction numM/denM; (0,1) = identity 0
    float numM[NP] = {0.0f, 0.0f}, denM[NP] = {1.0f, 1.0f};

    #pragma unroll 4
    for (int g = g0; g < g1; ++g) {
        const float4 t = sTB[g];               // broadcast ds_read_b128
        const float4 d = sTD[g];               // broadcast ds_read_b128
        #pragma unroll
        for (int k = 0; k < NP; ++k) {
            float iwr = fminf(pb[k].z, t.z) - fmaxf(pb[k].x, t.x);
            float ihr = fminf(pb[k].w, t.w) - fmaxf(pb[k].y, t.y);
            float inter = fmaxf(iwr, 0.0f) * fmaxf(ihr, 0.0f);
            float un  = (pa[k] + d.z) - inter;                     // >= 1
            float outer = ((pw[k] + d.x) - iwr) * ((ph[k] + d.y) - ihr);
            float num = __builtin_fmaf(un, un, inter * outer);
            float den = un * outer;                                // >= 1
            bool better = num * denM[k] > numM[k] * den;           // div-free max
            numM[k] = better ? num : numM[k];
            denM[k] = better ? den : denM[k];
        }
    }

    // generic tail if G > GCAP (never hit in bench shapes)
    for (int g = GL + wid; g < G; g += NW) {
        float4 t = tgt[(size_t)b * G + g];
        t.z += 1.0f; t.w += 1.0f;
        float tw = t.z - t.x, th = t.w - t.y, ta = tw * th;
        #pragma unroll
        for (int k = 0; k < NP; ++k) {
            float iwr = fminf(pb[k].z, t.z) - fmaxf(pb[k].x, t.x);
            float ihr = fminf(pb[k].w, t.w) - fmaxf(pb[k].y, t.y);
            float inter = fmaxf(iwr, 0.0f) * fmaxf(ihr, 0.0f);
            float un  = (pa[k] + ta) - inter;
            float outer = ((pw[k] + tw) - iwr) * ((ph[k] + th) - ihr);
            float num = __builtin_fmaf(un, un, inter * outer);
            float den = un * outer;
            bool better = num * denM[k] > numM[k] * den;
            numM[k] = better ? num : numM[k];
            denM[k] = better ? den : denM[k];
        }
    }

    // one reciprocal per pred, then cross-wave fold + block sum + one atomic
    #pragma unroll
    for (int k = 0; k < NP; ++k)
        sEx[k][tid] = numM[k] * __builtin_amdgcn_rcpf(denM[k]);
    __syncthreads();

    if (wid == 0) {
        float v = 0.0f;
        #pragma unroll
        for (int k = 0; k < NP; ++k) {
            float mm = sEx[k][lane];
            #pragma unroll
            for (int w = 1; w < NW; ++w) mm = fmaxf(mm, sEx[k][w * 64 + lane]);
            // per-pred loss = 1 - giou = 2 - (giou+1)
            v += (base + 64 * k + lane < P) ? (2.0f - mm) : 0.0f;
        }
        #pragma unroll
        for (int off = 32; off > 0; off >>= 1) v += __shfl_down(v, off, 64);
        if (lane == 0) atomicAdd(out, v * invB);
    }
}

extern "C" void kernel_launch(void* const* d_in, const int* in_sizes, int n_in,
                              void* d_out, int out_size, void* d_ws, size_t ws_size,
                              hipStream_t stream) {
    const float* imgs_box = (const float*)d_in[0];  // (B, G, 4) fp32 targets
    const float* pre_box  = (const float*)d_in[1];  // (B, P, 4) fp32 preds
    // d_in[2] = labels; only its length (B) matters.

    const int B = in_sizes[2];
    const int G = in_sizes[0] / (4 * B);
    const int P = in_sizes[1] / (4 * B);

    hipMemsetAsync(d_out, 0, sizeof(float), stream);

    const int pblocks = (P + NP * 64 - 1) / (NP * 64);   // 128 preds per block
    dim3 grid(pblocks, B);
    giou_kernel<<<grid, 512, 0, stream>>>(
        (const float4*)imgs_box, (const float4*)pre_box, (float*)d_out,
        P, G, 1.0f / (float)B);
}